// Round 5
// baseline (100.803 us; speedup 1.0000x reference)
//
#include <hip/hip_runtime.h>
#include <stdint.h>

#define NB 8
#define H 192
#define W 192
#define NPIX (NB * H * W) /* 294912 */
#define INFF 1e12f
#define NBLK 32     /* 4 blocks per batch image, each owns 48 columns */
#define TPB 384     /* 192 rows x 2 */
#define CWT 24      /* columns per thread */
#define GSTRIDE 49  /* padded LDS row stride (u32 words): 49k mod 32 covers all banks */

// ---------------------------------------------------------------------------
// Nearest set bit (clamped 255) from position w in a 192-bit row bitset
// (s2:s1:s0), inclusive. Proven in R4 (column version). Only called on
// sets where bit w is 0, so inclusive scan is safe. "None" => exactly 255.
// ---------------------------------------------------------------------------
__device__ __forceinline__ int hi_pos(uint64_t w0, uint64_t w1, uint64_t w2) {
  if (w2) return 191 - __builtin_clzll(w2);
  if (w1) return 127 - __builtin_clzll(w1);
  if (w0) return 63 - __builtin_clzll(w0);
  return -255;
}
__device__ __forceinline__ int lo_pos(uint64_t w0, uint64_t w1, uint64_t w2) {
  if (w0) return __builtin_ctzll(w0);
  if (w1) return 64 + __builtin_ctzll(w1);
  if (w2) return 128 + __builtin_ctzll(w2);
  return 447;
}
__device__ __forceinline__ int nearest_dist(uint64_t s0, uint64_t s1,
                                            uint64_t s2, int p) {
  int k = p >> 6, r = p & 63;
  uint64_t keepL = (2ull << r) - 1;
  uint64_t b0 = s0, b1 = s1, b2 = s2;
  if (k == 0) { b0 &= keepL; b1 = 0; b2 = 0; }
  else if (k == 1) { b1 &= keepL; b2 = 0; }
  else { b2 &= keepL; }
  int dbelow = p - hi_pos(b0, b1, b2);
  uint64_t keepU = (~0ull) << r;
  uint64_t a0 = s0, a1 = s1, a2 = s2;
  if (k == 0) { a0 &= keepU; }
  else if (k == 1) { a0 = 0; a1 &= keepU; }
  else { a0 = 0; a1 = 0; a2 &= keepU; }
  int dabove = lo_pos(a0, a1, a2) - p;
  return min(min(dbelow, dabove), 255);
}

__device__ __forceinline__ uint64_t shfl_xor_u64(uint64_t x, int m) {
  uint32_t lo = (uint32_t)x, hi = (uint32_t)(x >> 32);
  lo = __shfl_xor(lo, m, 64);
  hi = __shfl_xor(hi, m, 64);
  return ((uint64_t)hi << 32) | lo;
}

// ---------------------------------------------------------------------------
// Fused kernel. Block = (batch b, 48-column slab). Thread = (row r, half hf).
// Phase A: build full 192-bit row masks (pred: x>0, targ: t>0.5) — each
//   thread reads its half-row, partner halves exchanged via lane^1 shuffles
//   (pair threads are adjacent lanes: t = r*2+hf).
// Phase B: per pixel, packed u8 row-distances [dFp,dTp,dFt,dTt] into LDS
//   g[192][49] (255 = no-such-pixel-in-row sentinel; real dists <= 191).
// Phase C: vertical early-exit scan (proven R4 logic, axis-swapped) + fused
//   sigmoid/error/ratio loss; block reduce -> one partial per block.
// EDT separability is axis-order-symmetric, so W-pass-then-H-pass yields
// the identical exact EDT as the reference's H-then-W.
// ---------------------------------------------------------------------------
__global__ __launch_bounds__(TPB) void fused(
    const float* __restrict__ pred, const float* __restrict__ targ,
    float* __restrict__ partial) {
  int blk = blockIdx.x;
  int b = blk >> 2;
  int w0 = (blk & 3) * 48;
  int t = threadIdx.x;
  int r = t >> 1;   // row 0..191
  int hf = t & 1;   // half index (bitset half AND column half)
  __shared__ uint32_t g[H * GSTRIDE];  // 37632 B
  __shared__ float wsum[TPB / 64];

  // ---- Phase A ----
  const float* prow = pred + b * H * W + r * W + 96 * hf;
  const float* trow = targ + b * H * W + r * W + 96 * hf;
  uint64_t pl0 = 0, pl1 = 0, ql0 = 0, ql1 = 0;  // own 96 bits
#pragma unroll
  for (int i = 0; i < 96; i += 4) {
    float4 pv = *(const float4*)(prow + i);
    float4 tv = *(const float4*)(trow + i);
    uint64_t pb = (uint64_t)((int)(pv.x > 0.f) | ((int)(pv.y > 0.f) << 1) |
                             ((int)(pv.z > 0.f) << 2) | ((int)(pv.w > 0.f) << 3));
    uint64_t qb = (uint64_t)((int)(tv.x > .5f) | ((int)(tv.y > .5f) << 1) |
                             ((int)(tv.z > .5f) << 2) | ((int)(tv.w > .5f) << 3));
    if (i < 64) { pl0 |= pb << i; ql0 |= qb << i; }
    else        { pl1 |= pb << (i - 64); ql1 |= qb << (i - 64); }
  }
  uint64_t pm0 = shfl_xor_u64(pl0, 1), pm1 = shfl_xor_u64(pl1, 1);
  uint64_t qm0 = shfl_xor_u64(ql0, 1), qm1 = shfl_xor_u64(ql1, 1);
  // assemble full 192-bit row masks (own half covers [96*hf, 96*hf+96))
  uint64_t lo0 = hf ? pm0 : pl0, lo1 = hf ? pm1 : pl1;
  uint64_t hi0 = hf ? pl0 : pm0, hi1 = hf ? pl1 : pm1;
  uint64_t p0 = lo0;
  uint64_t p1 = (lo1 & 0xffffffffull) | (hi0 << 32);
  uint64_t p2 = (hi0 >> 32) | ((hi1 & 0xffffffffull) << 32);
  lo0 = hf ? qm0 : ql0; lo1 = hf ? qm1 : ql1;
  hi0 = hf ? ql0 : qm0; hi1 = hf ? ql1 : qm1;
  uint64_t q0 = lo0;
  uint64_t q1 = (lo1 & 0xffffffffull) | (hi0 << 32);
  uint64_t q2 = (hi0 >> 32) | ((hi1 & 0xffffffffull) << 32);

  // ---- Phase B ----
  int wl0 = CWT * hf;
#pragma unroll 4
  for (int i = 0; i < CWT; ++i) {
    int wl = wl0 + i;
    int w = w0 + wl;
    int k = w >> 6, rb = w & 63;
    uint64_t pw = (k == 0) ? p0 : ((k == 1) ? p1 : p2);
    uint64_t qw = (k == 0) ? q0 : ((k == 1) ? q1 : q2);
    int mp = (int)((pw >> rb) & 1);
    int mt = (int)((qw >> rb) & 1);
    uint64_t s0 = mp ? ~p0 : p0, s1 = mp ? ~p1 : p1, s2 = mp ? ~p2 : p2;
    int sp = nearest_dist(s0, s1, s2, w);  // dist to nearest opposite (pred)
    uint64_t u0 = mt ? ~q0 : q0, u1 = mt ? ~q1 : q1, u2 = mt ? ~q2 : q2;
    int st = nearest_dist(u0, u1, u2, w);  // dist to nearest opposite (targ)
    int dFp = mp ? sp : 0, dTp = mp ? 0 : sp;
    int dFt = mt ? st : 0, dTt = mt ? 0 : st;
    g[r * GSTRIDE + wl] = (uint32_t)dFp | ((uint32_t)dTp << 8) |
                          ((uint32_t)dFt << 16) | ((uint32_t)dTt << 24);
  }
  __syncthreads();

  // ---- Phase C ----
  float acc = 0.0f;
  const float* prow2 = pred + b * H * W + r * W + w0 + wl0;
  const float* trow2 = targ + b * H * W + r * W + w0 + wl0;
  for (int i = 0; i < CWT; ++i) {
    int wl = wl0 + i;
    float xv = prow2[i];
    float tv = trow2[i];
    int shp = (xv > 0.0f) ? 0 : 8;   // fg query needs dF field, bg needs dT
    int sht = (tv > 0.5f) ? 16 : 24;
    uint32_t own = g[r * GSTRIDE + wl];
    int dp = (own >> shp) & 255;
    int dt = (own >> sht) & 255;
    float bp = (dp == 255) ? INFF : (float)(dp * dp);
    float bt = (dt == 255) ? INFF : (float)(dt * dt);
    for (int dr = 1; dr < H; ++dr) {
      float rr = (float)(dr * dr);
      if (rr >= fmaxf(bp, bt)) break;  // farther rows can't improve either min
      int ru = r - dr, rd = r + dr;
      if (ru >= 0) {
        uint32_t v = g[ru * GSTRIDE + wl];
        int a = (v >> shp) & 255, c = (v >> sht) & 255;
        bp = fminf(bp, (a == 255) ? INFF : rr + (float)(a * a));
        bt = fminf(bt, (c == 255) ? INFF : rr + (float)(c * c));
      }
      if (rd < H) {
        uint32_t v = g[rd * GSTRIDE + wl];
        int a = (v >> shp) & 255, c = (v >> sht) & 255;
        bp = fminf(bp, (a == 255) ? INFF : rr + (float)(a * a));
        bt = fminf(bt, (c == 255) ? INFF : rr + (float)(c * c));
      }
    }
    float p = 1.0f / (1.0f + __expf(-xv));
    float e = p - tv;
    float pd = sqrtf(bp), td = sqrtf(bt);
    float s = pd + td;
    acc += e * e * (bp + bt) / (s * s);  // bp,bt >= 1 always: no 0/0
  }

  for (int off = 32; off > 0; off >>= 1) acc += __shfl_down(acc, off, 64);
  if ((t & 63) == 0) wsum[t >> 6] = acc;
  __syncthreads();
  if (t == 0) {
    float s = 0.0f;
#pragma unroll
    for (int j = 0; j < TPB / 64; ++j) s += wsum[j];
    partial[blk] = s;
  }
}

// ---------------------------------------------------------------------------
// Final reduce: 32 block partials -> mean. Plain store overwrites d_out
// poison; no init pass, no atomics.
// ---------------------------------------------------------------------------
__global__ __launch_bounds__(64) void reduce_pass(
    const float* __restrict__ partial, float* __restrict__ out) {
  int t = threadIdx.x;
  float s = (t < NBLK) ? partial[t] : 0.0f;
  for (int off = 32; off > 0; off >>= 1) s += __shfl_down(s, off, 64);
  if (t == 0) out[0] = s * (1.0f / (float)NPIX);
}

extern "C" void kernel_launch(void* const* d_in, const int* in_sizes, int n_in,
                              void* d_out, int out_size, void* d_ws, size_t ws_size,
                              hipStream_t stream) {
  const float* pred = (const float*)d_in[0];
  const float* targ = (const float*)d_in[1];
  float* out = (float*)d_out;
  float* partial = (float*)d_ws;  // NBLK floats, fully overwritten each call

  fused<<<NBLK, TPB, 0, stream>>>(pred, targ, partial);
  reduce_pass<<<1, 64, 0, stream>>>(partial, out);
}

// Round 6
// 96.539 us; speedup vs baseline: 1.0442x; 1.0442x over previous
//
#include <hip/hip_runtime.h>
#include <stdint.h>

#define B 8
#define H 192
#define W 192
#define NPIX (B * H * W) /* 294912 */
#define NROWS (B * H)    /* 1536 */
#define INFF 1e12f

// ---------------------------------------------------------------------------
// Nearest set bit (clamped to 255) from position h in a 192-bit column bitset
// (s2:s1:s0), inclusive of h. Proven exact in R4 (absmax 0). Uses
// __builtin_clzll/ctzll (ROCm __ffsll/__clzll overloads ambiguous for u64).
// ---------------------------------------------------------------------------
__device__ __forceinline__ int hi_pos(uint64_t w0, uint64_t w1, uint64_t w2) {
  if (w2) return 191 - __builtin_clzll(w2);
  if (w1) return 127 - __builtin_clzll(w1);
  if (w0) return 63 - __builtin_clzll(w0);
  return -255;  // none below -> distance >= 255
}
__device__ __forceinline__ int lo_pos(uint64_t w0, uint64_t w1, uint64_t w2) {
  if (w0) return __builtin_ctzll(w0);
  if (w1) return 64 + __builtin_ctzll(w1);
  if (w2) return 128 + __builtin_ctzll(w2);
  return 447;  // none above -> distance >= 255
}
__device__ __forceinline__ int nearest_dist(uint64_t s0, uint64_t s1,
                                            uint64_t s2, int h) {
  int k = h >> 6, r = h & 63;
  uint64_t keepL = (2ull << r) - 1;  // bits 0..r (r=63 -> all ones)
  uint64_t b0 = s0, b1 = s1, b2 = s2;
  if (k == 0) { b0 &= keepL; b1 = 0; b2 = 0; }
  else if (k == 1) { b1 &= keepL; b2 = 0; }
  else { b2 &= keepL; }
  int dbelow = h - hi_pos(b0, b1, b2);
  uint64_t keepU = (~0ull) << r;  // bits r..63
  uint64_t a0 = s0, a1 = s1, a2 = s2;
  if (k == 0) { a0 &= keepU; }
  else if (k == 1) { a0 = 0; a1 &= keepU; }
  else { a0 = 0; a1 = 0; a2 &= keepU; }
  int dabove = lo_pos(a0, a1, a2) - h;
  return min(min(dbelow, dabove), 255);
}

// ---------------------------------------------------------------------------
// K1: column pass (identical to the proven R4 kernel, plus zeroing the
// last-block arrival counter for K2 — stream order makes this safe).
// One block per (b, w) column, one thread per h. Three wave64 ballots build
// the 192-bit column masks; bit scans give the four per-pixel column
// distances, packed 4 x u8 (255 = none-in-column sentinel -> INF).
// 1536 blocks x 192 threads: full-chip parallelism (R5's 32-block fused
// variant proved low block count is fatal: 47 us @ 1.9% occupancy).
// ---------------------------------------------------------------------------
__global__ __launch_bounds__(192) void col_pass(
    const float* __restrict__ pred, const float* __restrict__ targ,
    uint32_t* __restrict__ g32, uint32_t* __restrict__ count) {
  int bw = blockIdx.x;  // 0..B*W
  int b = bw / W, w = bw % W;
  int h = threadIdx.x;
  if (bw == 0 && h == 0) *count = 0;  // d_ws is poisoned each call
  __shared__ uint64_t mP[3], mT[3];
  int idx = b * H * W + h * W + w;
  float xv = pred[idx];
  float tv = targ[idx];
  uint64_t bp = __ballot(xv > 0.0f);
  uint64_t bt = __ballot(tv > 0.5f);
  if ((h & 63) == 0) { mP[h >> 6] = bp; mT[h >> 6] = bt; }
  __syncthreads();
  uint64_t p0 = mP[0], p1 = mP[1], p2 = mP[2];
  uint64_t t0 = mT[0], t1 = mT[1], t2 = mT[2];
  int dFp = nearest_dist(~p0, ~p1, ~p2, h);  // nearest False (pred mask)
  int dTp = nearest_dist(p0, p1, p2, h);     // nearest True  (pred mask)
  int dFt = nearest_dist(~t0, ~t1, ~t2, h);
  int dTt = nearest_dist(t0, t1, t2, h);
  g32[idx] = (uint32_t)dFp | ((uint32_t)dTp << 8) | ((uint32_t)dFt << 16) |
             ((uint32_t)dTt << 24);
}

// ---------------------------------------------------------------------------
// K2: row pass + fused loss + last-block final reduce (replaces the R4
// standalone reduce kernel: one fewer graph node / dispatch gap).
// Scan logic identical to R4 (absmax 0). Each block stores its partial,
// __threadfence (device-scope release), one u32 atomicAdd arrival; the last
// arriving block acquires and reduces all 1536 partials -> d_out.
// ---------------------------------------------------------------------------
__global__ __launch_bounds__(192) void row_pass(
    const float* __restrict__ pred, const float* __restrict__ targ,
    const uint32_t* __restrict__ g32, float* __restrict__ partial,
    uint32_t* __restrict__ count, float* __restrict__ out) {
  int bh = blockIdx.x;
  int b = bh / H, h = bh % H;
  int w = threadIdx.x;
  __shared__ uint32_t sm[W];
  __shared__ float wsum[3];
  __shared__ int sdone;
  int base = b * H * W + h * W;
  uint32_t own = g32[base + w];
  sm[w] = own;
  float xv = pred[base + w];
  float tv = targ[base + w];
  __syncthreads();

  int shp = (xv > 0.0f) ? 0 : 8;   // fg pixel needs fg-EDT field, else bg
  int sht = (tv > 0.5f) ? 16 : 24;
  int dp = (own >> shp) & 255;
  int dt = (own >> sht) & 255;
  float bp = (dp == 255) ? INFF : (float)(dp * dp);
  float bt = (dt == 255) ? INFF : (float)(dt * dt);
  for (int r = 1; r < W; ++r) {
    float rr = (float)(r * r);
    if (rr >= fmaxf(bp, bt)) break;  // farther q can't improve either min
    int ql = w - r, qr = w + r;
    if (ql >= 0) {
      uint32_t v = sm[ql];
      int a = (v >> shp) & 255, c = (v >> sht) & 255;
      bp = fminf(bp, (a == 255) ? INFF : rr + (float)(a * a));
      bt = fminf(bt, (c == 255) ? INFF : rr + (float)(c * c));
    }
    if (qr < W) {
      uint32_t v = sm[qr];
      int a = (v >> shp) & 255, c = (v >> sht) & 255;
      bp = fminf(bp, (a == 255) ? INFF : rr + (float)(a * a));
      bt = fminf(bt, (c == 255) ? INFF : rr + (float)(c * c));
    }
  }

  float p = 1.0f / (1.0f + __expf(-xv));
  float e = p - tv;
  float err = e * e;
  float pd = sqrtf(bp), td = sqrtf(bt);
  float s = pd + td;
  float term = err * (bp + bt) / (s * s);  // bp,bt >= 1 always: no 0/0

  for (int off = 32; off > 0; off >>= 1) term += __shfl_down(term, off, 64);
  if ((w & 63) == 0) wsum[w >> 6] = term;
  __syncthreads();
  if (w == 0) {
    partial[bh] = wsum[0] + wsum[1] + wsum[2];
    __threadfence();                         // release partial before arrival
    uint32_t old = atomicAdd(count, 1u);     // device-scope by default
    sdone = (old == NROWS - 1);
  }
  __syncthreads();
  if (sdone) {  // last block: all partials written and visible
    __threadfence();  // acquire
    float acc = 0.0f;
    for (int i = w; i < NROWS; i += 192) acc += partial[i];
    for (int off = 32; off > 0; off >>= 1) acc += __shfl_down(acc, off, 64);
    if ((w & 63) == 0) wsum[w >> 6] = acc;
    __syncthreads();
    if (w == 0)
      out[0] = (wsum[0] + wsum[1] + wsum[2]) * (1.0f / (float)NPIX);
  }
}

extern "C" void kernel_launch(void* const* d_in, const int* in_sizes, int n_in,
                              void* d_out, int out_size, void* d_ws, size_t ws_size,
                              hipStream_t stream) {
  const float* pred = (const float*)d_in[0];
  const float* targ = (const float*)d_in[1];
  float* out = (float*)d_out;
  uint32_t* g32 = (uint32_t*)d_ws;                                  // NPIX u32
  float* partial = (float*)((char*)d_ws + (size_t)NPIX * 4);        // NROWS f32
  uint32_t* count = (uint32_t*)((char*)d_ws + (size_t)NPIX * 4 + NROWS * 4);

  col_pass<<<B * W, 192, 0, stream>>>(pred, targ, g32, count);
  row_pass<<<NROWS, 192, 0, stream>>>(pred, targ, g32, partial, count, out);
}

// Round 7
// 65.402 us; speedup vs baseline: 1.5413x; 1.4761x over previous
//
#include <hip/hip_runtime.h>
#include <stdint.h>

#define B 8
#define H 192
#define W 192
#define NPIX (B * H * W) /* 294912 */
#define NROWS (B * H)    /* 1536 */
#define NCOL (B * W)     /* 1536 */
#define INFF 1e12f

// ---------------------------------------------------------------------------
// Nearest set bit (clamped to 255) from position h in a 192-bit column bitset
// (s2:s1:s0), inclusive of h. Proven exact in R4 (absmax 0). Uses
// __builtin_clzll/ctzll (ROCm __ffsll/__clzll overloads ambiguous for u64).
// ---------------------------------------------------------------------------
__device__ __forceinline__ int hi_pos(uint64_t w0, uint64_t w1, uint64_t w2) {
  if (w2) return 191 - __builtin_clzll(w2);
  if (w1) return 127 - __builtin_clzll(w1);
  if (w0) return 63 - __builtin_clzll(w0);
  return -255;  // none below -> distance >= 255
}
__device__ __forceinline__ int lo_pos(uint64_t w0, uint64_t w1, uint64_t w2) {
  if (w0) return __builtin_ctzll(w0);
  if (w1) return 64 + __builtin_ctzll(w1);
  if (w2) return 128 + __builtin_ctzll(w2);
  return 447;  // none above -> distance >= 255
}
__device__ __forceinline__ int nearest_dist(uint64_t s0, uint64_t s1,
                                            uint64_t s2, int h) {
  int k = h >> 6, r = h & 63;
  uint64_t keepL = (2ull << r) - 1;  // bits 0..r (r=63 -> all ones)
  uint64_t b0 = s0, b1 = s1, b2 = s2;
  if (k == 0) { b0 &= keepL; b1 = 0; b2 = 0; }
  else if (k == 1) { b1 &= keepL; b2 = 0; }
  else { b2 &= keepL; }
  int dbelow = h - hi_pos(b0, b1, b2);
  uint64_t keepU = (~0ull) << r;  // bits r..63
  uint64_t a0 = s0, a1 = s1, a2 = s2;
  if (k == 0) { a0 &= keepU; }
  else if (k == 1) { a0 = 0; a1 &= keepU; }
  else { a0 = 0; a1 = 0; a2 &= keepU; }
  int dabove = lo_pos(a0, a1, a2) - h;
  return min(min(dbelow, dabove), 255);
}

// ---------------------------------------------------------------------------
// K1: column bitmask build. One block per (b, w) column, one thread per h.
// Three wave64 ballots per mask; each wave's lane 0 stores its 64-bit word
// straight to global (no LDS, no sync). SoA layout masks[j][b*W+w], j=0..2
// pred words, j=3..5 targ words -> K2's per-thread loads are coalesced.
// Total intermediate: 72 KB (vs R4's 1.18 MB g32 round-trip).
// NOTE (R6 lesson): no __threadfence / last-block patterns — 1536
// device-scope fences cost ~30 us on 8 non-coherent XCD L2s.
// ---------------------------------------------------------------------------
__global__ __launch_bounds__(192) void col_mask(
    const float* __restrict__ pred, const float* __restrict__ targ,
    uint64_t* __restrict__ masks) {
  int bw = blockIdx.x;  // 0..NCOL
  int b = bw / W, w = bw % W;
  int h = threadIdx.x;
  int idx = b * H * W + h * W + w;
  uint64_t bp = __ballot(pred[idx] > 0.0f);  // sigmoid(x)>0.5 <=> x>0
  uint64_t bt = __ballot(targ[idx] > 0.5f);
  if ((h & 63) == 0) {
    int wv = h >> 6;
    masks[wv * NCOL + bw] = bp;
    masks[(3 + wv) * NCOL + bw] = bt;
  }
}

// ---------------------------------------------------------------------------
// K2: row pass + fused loss. One block per (b, h) row, one thread per w.
// Thread w loads column w's 6 mask words (coalesced), derives its pixel's
// packed 4 x u8 column distances with TWO nearest-opposite bit scans
// (same-side distance is 0 by definition -> values identical to R4's 4-scan
// packing), shares via LDS, then the proven early-exit horizontal scan:
// D2[w] = min_q (w-q)^2 + d[q]^2, terminating when r^2 >= best (exact).
// Fused sigmoid/error/ratio term; one partial store per block (no atomics).
// ---------------------------------------------------------------------------
__global__ __launch_bounds__(192) void row_pass(
    const float* __restrict__ pred, const float* __restrict__ targ,
    const uint64_t* __restrict__ masks, float* __restrict__ partial) {
  int bh = blockIdx.x;
  int b = bh / H, h = bh % H;
  int w = threadIdx.x;
  __shared__ uint32_t sm[W];
  __shared__ float wsum[3];
  int cw = b * W + w;
  uint64_t p0 = masks[0 * NCOL + cw], p1 = masks[1 * NCOL + cw],
           p2 = masks[2 * NCOL + cw];
  uint64_t q0 = masks[3 * NCOL + cw], q1 = masks[4 * NCOL + cw],
           q2 = masks[5 * NCOL + cw];
  int base = b * H * W + h * W;
  float xv = pred[base + w];
  float tv = targ[base + w];

  int k = h >> 6, rb = h & 63;
  uint64_t pw = (k == 0) ? p0 : ((k == 1) ? p1 : p2);
  uint64_t qw = (k == 0) ? q0 : ((k == 1) ? q1 : q2);
  int mp = (int)((pw >> rb) & 1);  // == (xv > 0)
  int mt = (int)((qw >> rb) & 1);  // == (tv > 0.5)
  int sp = nearest_dist(mp ? ~p0 : p0, mp ? ~p1 : p1, mp ? ~p2 : p2, h);
  int st = nearest_dist(mt ? ~q0 : q0, mt ? ~q1 : q1, mt ? ~q2 : q2, h);
  int dFp = mp ? sp : 0, dTp = mp ? 0 : sp;
  int dFt = mt ? st : 0, dTt = mt ? 0 : st;
  uint32_t own = (uint32_t)dFp | ((uint32_t)dTp << 8) | ((uint32_t)dFt << 16) |
                 ((uint32_t)dTt << 24);
  sm[w] = own;
  __syncthreads();

  int shp = (xv > 0.0f) ? 0 : 8;   // fg pixel needs fg-EDT field, else bg
  int sht = (tv > 0.5f) ? 16 : 24;
  int dp = (own >> shp) & 255;
  int dt = (own >> sht) & 255;
  float bp = (dp == 255) ? INFF : (float)(dp * dp);
  float bt = (dt == 255) ? INFF : (float)(dt * dt);
  for (int r = 1; r < W; ++r) {
    float rr = (float)(r * r);
    if (rr >= fmaxf(bp, bt)) break;  // farther q can't improve either min
    int ql = w - r, qr = w + r;
    if (ql >= 0) {
      uint32_t v = sm[ql];
      int a = (v >> shp) & 255, c = (v >> sht) & 255;
      bp = fminf(bp, (a == 255) ? INFF : rr + (float)(a * a));
      bt = fminf(bt, (c == 255) ? INFF : rr + (float)(c * c));
    }
    if (qr < W) {
      uint32_t v = sm[qr];
      int a = (v >> shp) & 255, c = (v >> sht) & 255;
      bp = fminf(bp, (a == 255) ? INFF : rr + (float)(a * a));
      bt = fminf(bt, (c == 255) ? INFF : rr + (float)(c * c));
    }
  }

  float p = 1.0f / (1.0f + __expf(-xv));
  float e = p - tv;
  float err = e * e;
  float pd = sqrtf(bp), td = sqrtf(bt);
  float s = pd + td;
  float term = err * (bp + bt) / (s * s);  // bp,bt >= 1 always: no 0/0

  for (int off = 32; off > 0; off >>= 1) term += __shfl_down(term, off, 64);
  if ((w & 63) == 0) wsum[w >> 6] = term;
  __syncthreads();
  if (w == 0) partial[bh] = wsum[0] + wsum[1] + wsum[2];
}

// ---------------------------------------------------------------------------
// K3: final reduce of 1536 row partials -> mean. Plain store to d_out
// (overwrites harness poison; no init pass, no atomics, no fences).
// ---------------------------------------------------------------------------
__global__ __launch_bounds__(256) void reduce_pass(
    const float* __restrict__ partial, float* __restrict__ out) {
  int t = threadIdx.x;
  float s = 0.0f;
#pragma unroll
  for (int i = t; i < NROWS; i += 256) s += partial[i];
  for (int off = 32; off > 0; off >>= 1) s += __shfl_down(s, off, 64);
  __shared__ float ws[4];
  if ((t & 63) == 0) ws[t >> 6] = s;
  __syncthreads();
  if (t == 0) out[0] = (ws[0] + ws[1] + ws[2] + ws[3]) * (1.0f / (float)NPIX);
}

extern "C" void kernel_launch(void* const* d_in, const int* in_sizes, int n_in,
                              void* d_out, int out_size, void* d_ws, size_t ws_size,
                              hipStream_t stream) {
  const float* pred = (const float*)d_in[0];
  const float* targ = (const float*)d_in[1];
  float* out = (float*)d_out;
  uint64_t* masks = (uint64_t*)d_ws;                               // 6*NCOL u64
  float* partial = (float*)((char*)d_ws + (size_t)6 * NCOL * 8);   // NROWS f32

  col_mask<<<NCOL, 192, 0, stream>>>(pred, targ, masks);
  row_pass<<<NROWS, 192, 0, stream>>>(pred, targ, masks, partial);
  reduce_pass<<<1, 256, 0, stream>>>(partial, out);
}